// Round 5
// baseline (333.678 us; speedup 1.0000x reference)
//
#include <hip/hip_runtime.h>

// Problem constants (fixed by reference setup_inputs)
#define N_ROWS   65536      // 32*2048 flattened rows
#define D        256        // embedding_dim
#define D4       64         // D/4 in float4 units
#define M        1024       // n_embeddings
#define LOSS_OFF 16777216   // d_out offset of loss scalar
#define IDX_OFF  16777217   // d_out offset of indices (as float)
#define COMMIT_SCALE (0.25f / 16777216.0f)  // COMMITMENT_COST / numel(x)
#define E_SCALE  1024.0f    // exact pow2 pre-scale of e so e' in [-1,1]
#define C_SCALE  0.001953125f  // 2/1024: acc*C_SCALE == 2*C exactly

typedef _Float16 f16x8 __attribute__((ext_vector_type(8)));
typedef _Float16 f16x4 __attribute__((ext_vector_type(4)));
typedef float    f32x4 __attribute__((ext_vector_type(4)));

// Async global->LDS DMA, 16 B/lane: LDS dest = base + lane*16 (HW-implicit).
__device__ __forceinline__ void async_copy16(const void* g, void* l) {
    __builtin_amdgcn_global_load_lds(
        (const __attribute__((address_space(1))) unsigned int*)g,
        (__attribute__((address_space(3))) unsigned int*)l, 16, 0, 0);
}

// ===== numpy-exact fp32 row-norm emulation (validated rounds 2-4) =========
__device__ __forceinline__ float np_block128(const float* __restrict__ a, int l) {
    float r0 = __fmul_rn(a[l +   0], a[l +   0]);
    float r1 = __fmul_rn(a[l +  16], a[l +  16]);
    float r2 = __fmul_rn(a[l +  32], a[l +  32]);
    float r3 = __fmul_rn(a[l +  48], a[l +  48]);
    float r4 = __fmul_rn(a[l +  64], a[l +  64]);
    float r5 = __fmul_rn(a[l +  80], a[l +  80]);
    float r6 = __fmul_rn(a[l +  96], a[l +  96]);
    float r7 = __fmul_rn(a[l + 112], a[l + 112]);
    return __fadd_rn(__fadd_rn(__fadd_rn(r0, r1), __fadd_rn(r2, r3)),
                     __fadd_rn(__fadd_rn(r4, r5), __fadd_rn(r6, r7)));
}
__device__ __forceinline__ float np_reduce16(float v) {
    float s = __fadd_rn(v, __shfl_down(v, 8));
    s = __fadd_rn(s, __shfl_down(s, 4));
    s = __fadd_rn(s, __shfl_down(s, 2));
    s = __fadd_rn(s, __shfl_down(s, 1));
    return s;
}

// ---------------- kernel 1: np-exact row norms (coalesced via LDS) --------
__global__ __launch_bounds__(256) void norms_kernel(
    const float4* __restrict__ x4, const float4* __restrict__ emb4,
    float* __restrict__ bsq, float* __restrict__ esq,
    float* __restrict__ loss_slot) {
    __shared__ float rowbuf[16 * 260];   // stride 260: conflict-free np reads
    const int tid = threadIdx.x;
    const float4* src4;
    float* dst;
    if (blockIdx.x < 4096) {
        const int row0 = blockIdx.x * 16;
        src4 = x4 + (size_t)row0 * 64;
        dst = bsq + row0;
    } else {
        const int row0 = (blockIdx.x - 4096) * 16;
        src4 = emb4 + (size_t)row0 * 64;
        dst = esq + row0;
    }
    #pragma unroll
    for (int p = 0; p < 4; ++p) {
        const int f = tid + p * 256;     // 0..1023 float4s = 16 rows
        const int r = f >> 6, c4 = f & 63;
        *(float4*)&rowbuf[r * 260 + c4 * 4] = src4[f];
    }
    __syncthreads();
    const int l = tid & 15, g = tid >> 4;
    const float* base = &rowbuf[g * 260];
    const float v0 = np_block128(base, l);
    const float v1 = np_block128(base + 128, l);
    const float t0 = np_reduce16(v0);
    const float t1 = np_reduce16(v1);
    if (l == 0) dst[g] = __fadd_rn(t0, t1);
    if (blockIdx.x == 0 && tid == 0) *loss_slot = 0.0f;  // d_out is poisoned
}

// ---------------- kernel 2: split e' = 1024*e into SWIZZLED chunked planes
// Chunk (jt,kc) = 128 codes x 32 k = 8 KB contiguous (DMA-eligible).
// Within a chunk, 16-B unit for (code c, k-half q) sits at
//   u(c,q) = c*4 + (q ^ ((c>>1)&3))
// so a 16-lane ds_read_b128 phase hits each bank group exactly 2x (free).
__global__ __launch_bounds__(256) void esplit_kernel(
    const float4* __restrict__ emb4,
    _Float16* __restrict__ e_hi, _Float16* __restrict__ e_mid) {
    const int f = blockIdx.x * 256 + threadIdx.x;   // 0..65535 float4s
    const int code = f >> 6, k4 = f & 63;
    const int jt = code >> 7, c = code & 127;
    const int kc = k4 >> 3;
    const int q  = (k4 & 7) >> 1;                   // k-half within 32-k chunk
    const int u  = c * 4 + (q ^ ((c >> 1) & 3));    // swizzled 16-B unit
    float4 v = emb4[f];
    float a[4] = {v.x * E_SCALE, v.y * E_SCALE, v.z * E_SCALE, v.w * E_SCALE};
    f16x4 hi, mid;
    #pragma unroll
    for (int j = 0; j < 4; ++j) {
        _Float16 h = (_Float16)a[j];
        float r = __fsub_rn(a[j], (float)h);
        hi[j] = h;
        mid[j] = (_Float16)r;
    }
    const size_t ofs = (size_t)kc * 32768 + (size_t)jt * 4096
                     + (size_t)u * 8 + (k4 & 1) * 4;   // f16 units
    *(f16x4*)&e_hi[ofs]  = hi;
    *(f16x4*)&e_mid[ofs] = mid;
}

// ---------------- kernel 3: fp16-split MFMA distances + argmin + gather ---
// Block: 64 rows x all 1024 codes; 4 waves in 2x2 (wave = 32 rows x 64 codes).
// A (x) full-K in registers (launch_bounds(256,1): allocator may use up to
// 512 VGPRs -> no spills/remat; ~230 used -> still 2 waves/SIMD).
// B chunks DMA'd global->LDS, double-buffered, 1 barrier/chunk, swizzled.
// Epilogue fuses the quantized gather + commitment-loss partial.
__global__ __launch_bounds__(256, 1) void argmin_mfma_kernel(
    const float* __restrict__ x,
    const _Float16* __restrict__ e_hi, const _Float16* __restrict__ e_mid,
    const float* __restrict__ esq, const float* __restrict__ bsq,
    const float4* __restrict__ emb4,
    float* __restrict__ idx_out_f, float4* __restrict__ q4,
    float* __restrict__ loss_slot) {
    // buf[b]: hi plane f16[0..4096) = swizzled [code 0..127][k 0..31]; mid +4096
    __shared__ __attribute__((aligned(16))) _Float16 buf[2][8192];
    __shared__ float red_d[64][2];
    __shared__ int   red_i[64][2];
    __shared__ int   fin[64];
    __shared__ float wsum[4];

    const int tid = threadIdx.x;
    const int w = tid >> 6, lane = tid & 63;
    const int w_row = w >> 1, w_col = w & 1;
    const int lm = lane & 15, q = lane >> 4;     // A/B frag: [lm][k=q*8+j]
    const int row0 = blockIdx.x * 64;

    // ---- A fragments: rows row0 + w_row*32 + fm*16 + lm, split on the fly
    f16x8 a_hi[2][8], a_mid[2][8];
    #pragma unroll
    for (int fm = 0; fm < 2; ++fm) {
        const float* xr = x + (size_t)(row0 + w_row * 32 + fm * 16 + lm) * D + q * 8;
        #pragma unroll
        for (int kc = 0; kc < 8; ++kc) {
            float4 v0 = *(const float4*)(xr + kc * 32);
            float4 v1 = *(const float4*)(xr + kc * 32 + 4);
            float e[8] = {v0.x, v0.y, v0.z, v0.w, v1.x, v1.y, v1.z, v1.w};
            #pragma unroll
            for (int j = 0; j < 8; ++j) {
                _Float16 h = (_Float16)e[j];
                float r = __fsub_rn(e[j], (float)h);
                a_hi[fm][kc][j]  = h;
                a_mid[fm][kc][j] = (_Float16)r;
            }
        }
    }
    float bq[2][4];
    #pragma unroll
    for (int fm = 0; fm < 2; ++fm)
        #pragma unroll
        for (int r = 0; r < 4; ++r)
            bq[fm][r] = bsq[row0 + w_row * 32 + fm * 16 + q * 4 + r];

    float best[2][4] = {{3.0e38f, 3.0e38f, 3.0e38f, 3.0e38f},
                        {3.0e38f, 3.0e38f, 3.0e38f, 3.0e38f}};
    int bidx[2][4] = {{0, 0, 0, 0}, {0, 0, 0, 0}};

    // DMA one (jt,kc) chunk: 8 KB hi + 8 KB mid; wave w moves bytes
    // [w*2048, w*2048+2048) of each plane via 2 width-16 instrs.
    auto dma = [&](int c, int bsel) {
        const int jt = c >> 3, kc = c & 7;
        const size_t gofs = (size_t)kc * 65536 + (size_t)jt * 8192
                          + (size_t)w * 2048 + (size_t)lane * 16;   // bytes
        const char* gh = (const char*)e_hi + gofs;
        const char* gm = (const char*)e_mid + gofs;
        _Float16* lh  = &buf[bsel][w * 1024];          // byte ofs w*2048
        _Float16* lmm = &buf[bsel][4096 + w * 1024];
        async_copy16(gh, lh);
        async_copy16(gh + 1024, lh + 512);
        async_copy16(gm, lmm);
        async_copy16(gm + 1024, lmm + 512);
    };

    // Swizzled B-frag offsets for this lane (hoisted: fn-dependent only)
    int bo[4];
    #pragma unroll
    for (int fn = 0; fn < 4; ++fn) {
        const int c = w_col * 64 + fn * 16 + lm;
        bo[fn] = (c * 4 + (q ^ ((c >> 1) & 3))) * 8;   // f16 index of 16-B unit
    }

    dma(0, 0);
    for (int jt = 0; jt < 8; ++jt) {
        const int j0 = jt * 128;
        f32x4 acc[2][4] = {};
        for (int kc = 0; kc < 8; ++kc) {
            const int c = jt * 8 + kc;
            __syncthreads();               // buf[c&1] DMA landed; other buf free
            if (c < 63) dma(c + 1, (c + 1) & 1);   // prefetch (drained post-MFMA)
            const int bsel = c & 1;
            f16x8 bh[4], bm[4];
            #pragma unroll
            for (int fn = 0; fn < 4; ++fn) {
                bh[fn] = *(const f16x8*)&buf[bsel][bo[fn]];
                bm[fn] = *(const f16x8*)&buf[bsel][4096 + bo[fn]];
            }
            #pragma unroll
            for (int fm = 0; fm < 2; ++fm)
                #pragma unroll
                for (int fn = 0; fn < 4; ++fn) {
                    acc[fm][fn] = __builtin_amdgcn_mfma_f32_16x16x32_f16(
                        a_hi[fm][kc], bh[fn], acc[fm][fn], 0, 0, 0);
                    acc[fm][fn] = __builtin_amdgcn_mfma_f32_16x16x32_f16(
                        a_mid[fm][kc], bh[fn], acc[fm][fn], 0, 0, 0);
                    acc[fm][fn] = __builtin_amdgcn_mfma_f32_16x16x32_f16(
                        a_hi[fm][kc], bm[fn], acc[fm][fn], 0, 0, 0);
                }
        }
        // Epilogue: reference-rounded d, running argmin (ascending j, strict <)
        #pragma unroll
        for (int fn = 0; fn < 4; ++fn) {
            const int j = j0 + w_col * 64 + fn * 16 + lm;
            const float eq = esq[j];
            #pragma unroll
            for (int fm = 0; fm < 2; ++fm)
                #pragma unroll
                for (int r = 0; r < 4; ++r) {
                    const float d = __fsub_rn(__fadd_rn(eq, bq[fm][r]),
                                              acc[fm][fn][r] * C_SCALE);
                    if (d < best[fm][r]) { best[fm][r] = d; bidx[fm][r] = j; }
                }
        }
    }
    // Reduce across the 16 col-lanes of each quad (lexicographic min)
    #pragma unroll
    for (int fm = 0; fm < 2; ++fm)
        #pragma unroll
        for (int r = 0; r < 4; ++r) {
            float d = best[fm][r]; int i = bidx[fm][r];
            #pragma unroll
            for (int mv = 1; mv <= 8; mv <<= 1) {
                const float d2 = __shfl_xor(d, mv, 64);
                const int   i2 = __shfl_xor(i, mv, 64);
                if (d2 < d || (d2 == d && i2 < i)) { d = d2; i = i2; }
            }
            best[fm][r] = d; bidx[fm][r] = i;
        }
    __syncthreads();
    if (lm == 0) {
        #pragma unroll
        for (int fm = 0; fm < 2; ++fm)
            #pragma unroll
            for (int r = 0; r < 4; ++r) {
                const int rl = w_row * 32 + fm * 16 + q * 4 + r;
                red_d[rl][w_col] = best[fm][r];
                red_i[rl][w_col] = bidx[fm][r];
            }
    }
    __syncthreads();
    if (tid < 64) {
        float d0 = red_d[tid][0]; int i0 = red_i[tid][0];
        const float d1 = red_d[tid][1]; const int i1 = red_i[tid][1];
        if (d1 < d0 || (d1 == d0 && i1 < i0)) { d0 = d1; i0 = i1; }
        fin[tid] = i0;
        idx_out_f[row0 + tid] = (float)i0;
    }
    __syncthreads();

    // ---- fused gather + commitment-loss partial --------------------------
    // f = tid + p*256: per wave f>>6 is constant -> emb row is wave-uniform,
    // all global accesses fully coalesced.
    const float4* x4 = (const float4*)x;
    const size_t base4 = (size_t)row0 * D4;
    float lacc = 0.0f;
    #pragma unroll
    for (int p = 0; p < 16; ++p) {
        const int f = tid + p * 256;      // 0..4095 float4 within block
        const int r = f >> 6, c4 = f & 63;
        const int e = fin[r];
        float4 qv = emb4[(size_t)e * D4 + c4];
        float4 xv = x4[base4 + f];
        q4[base4 + f] = qv;
        const float dx = xv.x - qv.x, dy = xv.y - qv.y;
        const float dz = xv.z - qv.z, dw = xv.w - qv.w;
        lacc += dx * dx + dy * dy + dz * dz + dw * dw;
    }
    #pragma unroll
    for (int off = 32; off; off >>= 1) lacc += __shfl_down(lacc, off, 64);
    if (lane == 0) wsum[w] = lacc;
    __syncthreads();
    if (tid == 0)
        atomicAdd(loss_slot, (wsum[0] + wsum[1] + wsum[2] + wsum[3]) * COMMIT_SCALE);
}

extern "C" void kernel_launch(void* const* d_in, const int* in_sizes, int n_in,
                              void* d_out, int out_size, void* d_ws, size_t ws_size,
                              hipStream_t stream) {
    const float* x   = (const float*)d_in[0];    // 32*2048*256
    const float* emb = (const float*)d_in[1];    // 1024*256
    float* out = (float*)d_out;
    // ws layout (16B-aligned): bsq | esq | e_hi(chunked) | e_mid(chunked)
    float*    bsq  = (float*)d_ws;                       // N_ROWS f32
    float*    esq  = bsq + N_ROWS;                       // M f32
    _Float16* e_hi = (_Float16*)(esq + M);               // M*D f16 chunked
    _Float16* e_mid = e_hi + (size_t)M * D;              // M*D f16 chunked

    norms_kernel<<<4096 + M / 16, 256, 0, stream>>>((const float4*)x,
                                                    (const float4*)emb,
                                                    bsq, esq, out + LOSS_OFF);
    esplit_kernel<<<M * D / 4 / 256, 256, 0, stream>>>((const float4*)emb,
                                                       e_hi, e_mid);
    argmin_mfma_kernel<<<N_ROWS / 64, 256, 0, stream>>>(x, e_hi, e_mid,
                                                        esq, bsq,
                                                        (const float4*)emb,
                                                        out + IDX_OFF,
                                                        (float4*)out,
                                                        out + LOSS_OFF);
}